// Round 4
// baseline (187.436 us; speedup 1.0000x reference)
//
#include <hip/hip_runtime.h>

#define NQ   10000
#define BSZ  2
#define DIM  256
#define NH   8
#define HD   32
#define NLV  4
#define NPT  4
#define NV   13294           // 10000 + 2500 + 625 + 169
#define MT   (BSZ*NQ)        // 20000 rows
#define NOUT 384             // 256 offsets + 128 attn logits

typedef float  floatx4 __attribute__((ext_vector_type(4)));
typedef int    intx4   __attribute__((ext_vector_type(4)));
typedef __bf16 bf16x8  __attribute__((ext_vector_type(8)));

__device__ __forceinline__ unsigned short f32_to_bf16(float f) {
  unsigned int u = __float_as_uint(f);
  u += 0x7FFFu + ((u >> 16) & 1u);   // RNE
  return (unsigned short)(u >> 16);
}

// ---------------- fused cast+GEMM: raw = Q @ [W_off;W_attn]^T + bias ----------------
// block tile 64(m) x 128(n), BK=32, 4 waves; wave w owns m-rows [w*16, w*16+16).
// f32 -> bf16 conversion happens in registers during LDS staging (kills cast kernel).
// grid = (3, 313): n fastest so consecutive blocks share the A tile in L2.
__global__ __launch_bounds__(256) void gemm_kernel(
    const float* __restrict__ query, const float* __restrict__ W_off,
    const float* __restrict__ W_attn,
    const float* __restrict__ b_off, const float* __restrict__ b_attn,
    float* __restrict__ raw) {
  __shared__ unsigned short As[64][40];    // +8 pad
  __shared__ unsigned short Bs[128][40];
  const int n0 = blockIdx.x * 128;
  const int m0 = blockIdx.y * 64;
  const int tid  = threadIdx.x;
  const int wave = tid >> 6;
  const int lane = tid & 63;
  const int quad = lane >> 4;
  const int l16  = lane & 15;
  floatx4 acc[8] = {};
  const int ar = tid >> 2;        // 0..63
  const int ac = (tid & 3) * 8;   // 0,8,16,24
  const int br = tid >> 1;        // 0..127
  const int bc = (tid & 1) * 16;  // 0,16
  // block-uniform W source: rows [n0, n0+128) are entirely in W_off or W_attn
  const float* __restrict__ Wsrc =
      (n0 < 256) ? (W_off + (size_t)n0 * DIM) : (W_attn + (size_t)(n0 - 256) * DIM);

  for (int k0 = 0; k0 < DIM; k0 += 32) {
    // ---- A stage: 8 f32 -> 8 bf16 per thread ----
    {
      int gm = m0 + ar;
      floatx4 a0 = {}, a1 = {};
      if (gm < MT) {
        const float* src = query + (size_t)gm * DIM + k0 + ac;
        a0 = *(const floatx4*)src;
        a1 = *(const floatx4*)(src + 4);
      }
      unsigned short t[8];
      t[0]=f32_to_bf16(a0.x); t[1]=f32_to_bf16(a0.y); t[2]=f32_to_bf16(a0.z); t[3]=f32_to_bf16(a0.w);
      t[4]=f32_to_bf16(a1.x); t[5]=f32_to_bf16(a1.y); t[6]=f32_to_bf16(a1.z); t[7]=f32_to_bf16(a1.w);
      *(uint4*)&As[ar][ac] = *(const uint4*)t;
    }
    // ---- B stage: 16 f32 -> 16 bf16 per thread ----
    {
      const float* src = Wsrc + (size_t)br * DIM + k0 + bc;
      floatx4 b0 = *(const floatx4*)src;
      floatx4 b1 = *(const floatx4*)(src + 4);
      floatx4 b2 = *(const floatx4*)(src + 8);
      floatx4 b3 = *(const floatx4*)(src + 12);
      unsigned short t[16];
      t[0]=f32_to_bf16(b0.x);  t[1]=f32_to_bf16(b0.y);  t[2]=f32_to_bf16(b0.z);  t[3]=f32_to_bf16(b0.w);
      t[4]=f32_to_bf16(b1.x);  t[5]=f32_to_bf16(b1.y);  t[6]=f32_to_bf16(b1.z);  t[7]=f32_to_bf16(b1.w);
      t[8]=f32_to_bf16(b2.x);  t[9]=f32_to_bf16(b2.y);  t[10]=f32_to_bf16(b2.z); t[11]=f32_to_bf16(b2.w);
      t[12]=f32_to_bf16(b3.x); t[13]=f32_to_bf16(b3.y); t[14]=f32_to_bf16(b3.z); t[15]=f32_to_bf16(b3.w);
      *(uint4*)&Bs[br][bc]     = *(const uint4*)t;
      *(uint4*)&Bs[br][bc + 8] = *(const uint4*)(t + 8);
    }
    __syncthreads();
    // A frag: A[m=l16][k=quad*8+j]
    bf16x8 a = *(const bf16x8*)&As[wave*16 + l16][quad*8];
    #pragma unroll
    for (int nt = 0; nt < 8; nt++) {
      bf16x8 b = *(const bf16x8*)&Bs[nt*16 + l16][quad*8];
      acc[nt] = __builtin_amdgcn_mfma_f32_16x16x32_bf16(a, b, acc[nt], 0, 0, 0);
    }
    __syncthreads();
  }
  // C/D layout: row = quad*4 + r, col = l16
  #pragma unroll
  for (int nt = 0; nt < 8; nt++) {
    int gn = n0 + nt*16 + l16;
    float bias = (gn < 256) ? b_off[gn] : b_attn[gn - 256];
    #pragma unroll
    for (int r = 0; r < 4; r++) {
      int gm = m0 + wave*16 + quad*4 + r;
      if (gm < MT) raw[(size_t)gm*NOUT + gn] = acc[nt][r] + bias;
    }
  }
}

// ---------------- softmax + bilinear sampling + fused output transpose ----------------
// Block = 256 threads handles FOUR queries.
//  1) 512 slots (ql,h,l,p): px,py,logit -> LDS
//  2) softmax per (ql,h) over 16 logits (32 threads)
//  3) tap table: byte-offset (incl. h*128; OOB -> 0) and aw-folded weight,
//     row layout [(ql*8+h)*132 + pt*8] = {off0..3, w0..3} (conflict-free broadcast)
//  4) accumulate: wave=ql, lane=(h,cq): 16 x (2 ds_read_b128 +
//     4 global_load_dwordx4 + 16 fma); result -> padded LDS transpose buffer
//  5) thread=ch: float4 store out[b][ch][q0..q0+3] (16B-aligned, q-contiguous)
__global__ __launch_bounds__(256) void sample_kernel(
    const float* __restrict__ raw, const float* __restrict__ value,
    const float* __restrict__ refp, float* __restrict__ out) {
  const int b  = blockIdx.y;
  const int q0 = blockIdx.x * 4;
  const int mbase = b * NQ + q0;
  const int tid = threadIdx.x;

  // px/py/logit are dead after phase 3; outbuf (4*280 = 1120 f) aliases them.
  __shared__ union {
    struct { float px[512]; float py[512]; float logit[512]; } a;
    float outbuf[1120];   // [ql][h*33 + c], row stride 280
  } u;
  __shared__ int s_tab[4 * 8 * 132];   // 16896 B

  const int WLI[4] = {100, 50, 25, 13};
  const int STI[4] = {0, 10000, 12500, 13125};

  // ---- phase 1: sampling coords + logits ----
  #pragma unroll
  for (int it = 0; it < 2; ++it) {
    int slot = it * 256 + tid;
    int ql = slot >> 7, r = slot & 127, h = r >> 4, lp = r & 15, l = lp >> 2, p = lp & 3;
    int m = mbase + ql;
    const float* rp = raw + (size_t)m * NOUT;
    float offx = rp[h*32 + l*8 + p*2 + 0];
    float offy = rp[h*32 + l*8 + p*2 + 1];
    u.a.logit[slot] = rp[256 + h*16 + lp];
    float Wl = (float)WLI[l];
    float rx = refp[(m*NLV + l)*2 + 0];
    float ry = refp[(m*NLV + l)*2 + 1];
    // (ref + off/W)*2-1 -> pixel (align_corners=False): ref*W + off - 0.5
    u.a.px[slot] = rx * Wl + offx - 0.5f;
    u.a.py[slot] = ry * Wl + offy - 0.5f;
  }
  __syncthreads();

  // ---- phase 2: softmax over 16 logits per (ql,h), in place ----
  if (tid < 32) {
    int base = tid * 16;   // tid = ql*8+h
    float mx = -1e30f;
    #pragma unroll
    for (int i = 0; i < 16; i++) mx = fmaxf(mx, u.a.logit[base + i]);
    float s = 0.f;
    float e[16];
    #pragma unroll
    for (int i = 0; i < 16; i++) { e[i] = expf(u.a.logit[base + i] - mx); s += e[i]; }
    float inv = 1.f / s;
    #pragma unroll
    for (int i = 0; i < 16; i++) u.a.logit[base + i] = e[i] * inv;
  }
  __syncthreads();

  // ---- phase 3: tap table (byte offsets + folded weights) ----
  #pragma unroll
  for (int it = 0; it < 2; ++it) {
    int slot = it * 256 + tid;
    int ql = slot >> 7, r = slot & 127, h = r >> 4, lp = r & 15, l = lp >> 2;
    float px = u.a.px[slot], py = u.a.py[slot], aw = u.a.logit[slot];
    float x0f = floorf(px), y0f = floorf(py);
    int x0 = (int)x0f, y0 = (int)y0f;
    float wx1 = px - x0f, wx0 = 1.f - wx1;
    float wy1 = py - y0f, wy0 = 1.f - wy1;
    int Wl = WLI[l], STl = STI[l];
    int row = (ql*8 + h) * 132 + lp * 8;
    #pragma unroll
    for (int t = 0; t < 4; ++t) {
      int xi = x0 + (t & 1), yi = y0 + (t >> 1);
      bool inb = (xi >= 0) & (xi < Wl) & (yi >= 0) & (yi < Wl);
      int off = inb ? ((STl + yi*Wl + xi) * 1024 + h * 128) : 0;  // bytes
      float w = inb ? (aw * ((t & 1) ? wx1 : wx0) * ((t >> 1) ? wy1 : wy0)) : 0.f;
      s_tab[row + t]     = off;
      s_tab[row + 4 + t] = __float_as_int(w);
    }
  }
  __syncthreads();

  // ---- phase 4: accumulate; wave = query, lane = (h, cq) ----
  {
    const int ql = tid >> 6, lane = tid & 63, h = lane >> 3, cq = lane & 7;
    const char* vb = (const char*)value + (size_t)b * (NV*NH*HD*4) + cq * 16;
    floatx4 acc = {0.f, 0.f, 0.f, 0.f};
    const int rbase = (ql*8 + h) * 132;
    #pragma unroll 4
    for (int pt = 0; pt < 16; ++pt) {
      intx4   offs = *(const intx4*)  &s_tab[rbase + pt*8];
      floatx4 ws   = *(const floatx4*)&s_tab[rbase + pt*8 + 4];
      floatx4 v0 = *(const floatx4*)(vb + offs.x);
      floatx4 v1 = *(const floatx4*)(vb + offs.y);
      floatx4 v2 = *(const floatx4*)(vb + offs.z);
      floatx4 v3 = *(const floatx4*)(vb + offs.w);
      acc += ws.x * v0;
      acc += ws.y * v1;
      acc += ws.z * v2;
      acc += ws.w * v3;
    }
    // transpose staging: outbuf[ql*280 + h*33 + (cq*4+j)]
    // banks: (24*ql + h + 4*cq + j) mod 32 -> <=2-way (free)
    int obase = ql*280 + h*33 + cq*4;
    u.outbuf[obase + 0] = acc.x;
    u.outbuf[obase + 1] = acc.y;
    u.outbuf[obase + 2] = acc.z;
    u.outbuf[obase + 3] = acc.w;
  }
  __syncthreads();

  // ---- phase 5: out[b][ch][q0..q0+3], one float4 per thread ----
  {
    const int ch = tid, h = ch >> 5, c = ch & 31;
    floatx4 o;
    o.x = u.outbuf[0*280 + h*33 + c];
    o.y = u.outbuf[1*280 + h*33 + c];
    o.z = u.outbuf[2*280 + h*33 + c];
    o.w = u.outbuf[3*280 + h*33 + c];
    *(floatx4*)&out[((size_t)(b*DIM + ch))*NQ + q0] = o;
  }
}

extern "C" void kernel_launch(void* const* d_in, const int* in_sizes, int n_in,
                              void* d_out, int out_size, void* d_ws, size_t ws_size,
                              hipStream_t stream) {
  const float* query  = (const float*)d_in[0];
  const float* value  = (const float*)d_in[1];
  const float* refp   = (const float*)d_in[2];
  // d_in[3] = spatial_shapes (constants hardcoded)
  const float* W_off  = (const float*)d_in[4];
  const float* b_off  = (const float*)d_in[5];
  const float* W_attn = (const float*)d_in[6];
  const float* b_attn = (const float*)d_in[7];
  float* out = (float*)d_out;

  float* raw = (float*)d_ws;   // 20000*384*4 = 30,720,000 B

  hipLaunchKernelGGL(gemm_kernel, dim3(3, 313), dim3(256), 0, stream,
                     query, W_off, W_attn, b_off, b_attn, raw);
  hipLaunchKernelGGL(sample_kernel, dim3(NQ / 4, BSZ), dim3(256), 0, stream,
                     raw, value, refp, out);
}

// Round 5
// 178.488 us; speedup vs baseline: 1.0501x; 1.0501x over previous
//
#include <hip/hip_runtime.h>

#define NQ   10000
#define BSZ  2
#define DIM  256
#define NH   8
#define HD   32
#define NLV  4
#define NPT  4
#define NV   13294           // 10000 + 2500 + 625 + 169
#define MT   (BSZ*NQ)        // 20000 rows
#define NOUT 384             // 256 offsets + 128 attn logits

typedef float  floatx4 __attribute__((ext_vector_type(4)));
typedef int    intx4   __attribute__((ext_vector_type(4)));
typedef __bf16 bf16x8  __attribute__((ext_vector_type(8)));

__device__ __forceinline__ unsigned short f32_to_bf16(float f) {
  unsigned int u = __float_as_uint(f);
  u += 0x7FFFu + ((u >> 16) & 1u);   // RNE
  return (unsigned short)(u >> 16);
}

// ---------------- fused cast+GEMM: raw = Q @ [W_off;W_attn]^T + bias ----------------
// block tile 64(m) x 128(n), BK=32, 4 waves; f32->bf16 in registers during staging.
__global__ __launch_bounds__(256) void gemm_kernel(
    const float* __restrict__ query, const float* __restrict__ W_off,
    const float* __restrict__ W_attn,
    const float* __restrict__ b_off, const float* __restrict__ b_attn,
    float* __restrict__ raw) {
  __shared__ unsigned short As[64][40];    // +8 pad
  __shared__ unsigned short Bs[128][40];
  const int n0 = blockIdx.x * 128;
  const int m0 = blockIdx.y * 64;
  const int tid  = threadIdx.x;
  const int wave = tid >> 6;
  const int lane = tid & 63;
  const int quad = lane >> 4;
  const int l16  = lane & 15;
  floatx4 acc[8] = {};
  const int ar = tid >> 2;        // 0..63
  const int ac = (tid & 3) * 8;   // 0,8,16,24
  const int br = tid >> 1;        // 0..127
  const int bc = (tid & 1) * 16;  // 0,16
  const float* __restrict__ Wsrc =
      (n0 < 256) ? (W_off + (size_t)n0 * DIM) : (W_attn + (size_t)(n0 - 256) * DIM);

  for (int k0 = 0; k0 < DIM; k0 += 32) {
    {
      int gm = m0 + ar;
      floatx4 a0 = {}, a1 = {};
      if (gm < MT) {
        const float* src = query + (size_t)gm * DIM + k0 + ac;
        a0 = *(const floatx4*)src;
        a1 = *(const floatx4*)(src + 4);
      }
      unsigned short t[8];
      t[0]=f32_to_bf16(a0.x); t[1]=f32_to_bf16(a0.y); t[2]=f32_to_bf16(a0.z); t[3]=f32_to_bf16(a0.w);
      t[4]=f32_to_bf16(a1.x); t[5]=f32_to_bf16(a1.y); t[6]=f32_to_bf16(a1.z); t[7]=f32_to_bf16(a1.w);
      *(uint4*)&As[ar][ac] = *(const uint4*)t;
    }
    {
      const float* src = Wsrc + (size_t)br * DIM + k0 + bc;
      floatx4 b0 = *(const floatx4*)src;
      floatx4 b1 = *(const floatx4*)(src + 4);
      floatx4 b2 = *(const floatx4*)(src + 8);
      floatx4 b3 = *(const floatx4*)(src + 12);
      unsigned short t[16];
      t[0]=f32_to_bf16(b0.x);  t[1]=f32_to_bf16(b0.y);  t[2]=f32_to_bf16(b0.z);  t[3]=f32_to_bf16(b0.w);
      t[4]=f32_to_bf16(b1.x);  t[5]=f32_to_bf16(b1.y);  t[6]=f32_to_bf16(b1.z);  t[7]=f32_to_bf16(b1.w);
      t[8]=f32_to_bf16(b2.x);  t[9]=f32_to_bf16(b2.y);  t[10]=f32_to_bf16(b2.z); t[11]=f32_to_bf16(b2.w);
      t[12]=f32_to_bf16(b3.x); t[13]=f32_to_bf16(b3.y); t[14]=f32_to_bf16(b3.z); t[15]=f32_to_bf16(b3.w);
      *(uint4*)&Bs[br][bc]     = *(const uint4*)t;
      *(uint4*)&Bs[br][bc + 8] = *(const uint4*)(t + 8);
    }
    __syncthreads();
    bf16x8 a = *(const bf16x8*)&As[wave*16 + l16][quad*8];
    #pragma unroll
    for (int nt = 0; nt < 8; nt++) {
      bf16x8 b = *(const bf16x8*)&Bs[nt*16 + l16][quad*8];
      acc[nt] = __builtin_amdgcn_mfma_f32_16x16x32_bf16(a, b, acc[nt], 0, 0, 0);
    }
    __syncthreads();
  }
  #pragma unroll
  for (int nt = 0; nt < 8; nt++) {
    int gn = n0 + nt*16 + l16;
    float bias = (gn < 256) ? b_off[gn] : b_attn[gn - 256];
    #pragma unroll
    for (int r = 0; r < 4; r++) {
      int gm = m0 + wave*16 + quad*4 + r;
      if (gm < MT) raw[(size_t)gm*NOUT + gn] = acc[nt][r] + bias;
    }
  }
}

// ---------------- softmax + bilinear sampling ----------------
// Block = 256 threads, FOUR queries. LDS slimmed to 19,072 B -> 8 blocks/CU:
//  1) 512 slots (ql,h,l,p): logits -> s_aw (17-stride); px,py stay in REGISTERS
//  2) softmax per (ql,h) over 16 logits (32 threads), in place in s_aw
//  3) tap table from register px,py + aw: [(ql*8+h)*132 + pt*8] = {off0..3, w0..3}
//  4) accumulate: wave=ql, lane=(h,cq): 16 x (2 ds_read_b128 +
//     4 global_load_dwordx4 + 16 fma); coalesced float4 store to tmp[b,q,ch]
__global__ __launch_bounds__(256) void sample_kernel(
    const float* __restrict__ raw, const float* __restrict__ value,
    const float* __restrict__ refp, float* __restrict__ tmp) {
  const int b  = blockIdx.y;
  const int q0 = blockIdx.x * 4;
  const int mbase = b * NQ + q0;
  const int tid = threadIdx.x;

  __shared__ int   s_tab[4 * 8 * 132];   // 16,896 B
  __shared__ float s_aw[544];            //  2,176 B (rows of 17: conflict-free)

  const int WLI[4] = {100, 50, 25, 13};
  const int STI[4] = {0, 10000, 12500, 13125};

  float rpx[2], rpy[2];   // px,py for this thread's two slots, live across barriers

  // ---- phase 1: coords (registers) + logits (LDS) ----
  #pragma unroll
  for (int it = 0; it < 2; ++it) {
    int slot = it * 256 + tid;
    int ql = slot >> 7, r = slot & 127, h = r >> 4, lp = r & 15, l = lp >> 2, p = lp & 3;
    int m = mbase + ql;
    const float* rp = raw + (size_t)m * NOUT;
    float offx = rp[h*32 + l*8 + p*2 + 0];
    float offy = rp[h*32 + l*8 + p*2 + 1];
    s_aw[(ql*8 + h)*17 + lp] = rp[256 + h*16 + lp];
    float Wl = (float)WLI[l];
    float rx = refp[(m*NLV + l)*2 + 0];
    float ry = refp[(m*NLV + l)*2 + 1];
    // (ref + off/W)*2-1 -> pixel (align_corners=False): ref*W + off - 0.5
    rpx[it] = rx * Wl + offx - 0.5f;
    rpy[it] = ry * Wl + offy - 0.5f;
  }
  __syncthreads();

  // ---- phase 2: softmax over 16 logits per (ql,h), in place ----
  if (tid < 32) {
    int base = tid * 17;   // tid = ql*8+h
    float mx = -1e30f;
    #pragma unroll
    for (int i = 0; i < 16; i++) mx = fmaxf(mx, s_aw[base + i]);
    float s = 0.f;
    float e[16];
    #pragma unroll
    for (int i = 0; i < 16; i++) { e[i] = expf(s_aw[base + i] - mx); s += e[i]; }
    float inv = 1.f / s;
    #pragma unroll
    for (int i = 0; i < 16; i++) s_aw[base + i] = e[i] * inv;
  }
  __syncthreads();

  // ---- phase 3: tap table (byte offsets + aw-folded weights) ----
  #pragma unroll
  for (int it = 0; it < 2; ++it) {
    int slot = it * 256 + tid;
    int ql = slot >> 7, r = slot & 127, h = r >> 4, lp = r & 15, l = lp >> 2;
    float aw = s_aw[(ql*8 + h)*17 + lp];
    float px = rpx[it], py = rpy[it];
    float x0f = floorf(px), y0f = floorf(py);
    int x0 = (int)x0f, y0 = (int)y0f;
    float wx1 = px - x0f, wx0 = 1.f - wx1;
    float wy1 = py - y0f, wy0 = 1.f - wy1;
    int Wl = WLI[l], STl = STI[l];
    int row = (ql*8 + h) * 132 + lp * 8;
    #pragma unroll
    for (int t = 0; t < 4; ++t) {
      int xi = x0 + (t & 1), yi = y0 + (t >> 1);
      bool inb = (xi >= 0) & (xi < Wl) & (yi >= 0) & (yi < Wl);
      int off = inb ? ((STl + yi*Wl + xi) * 1024 + h * 128) : 0;  // bytes
      float w = inb ? (aw * ((t & 1) ? wx1 : wx0) * ((t >> 1) ? wy1 : wy0)) : 0.f;
      s_tab[row + t]     = off;
      s_tab[row + 4 + t] = __float_as_int(w);
    }
  }
  __syncthreads();

  // ---- phase 4: accumulate; wave = query, lane = (h, cq) ----
  const int ql = tid >> 6, lane = tid & 63, h = lane >> 3, cq = lane & 7;
  const char* vb = (const char*)value + (size_t)b * (NV*NH*HD*4) + cq * 16;
  floatx4 acc = {0.f, 0.f, 0.f, 0.f};
  const int rbase = (ql*8 + h) * 132;
  #pragma unroll 4
  for (int pt = 0; pt < 16; ++pt) {
    intx4   offs = *(const intx4*)  &s_tab[rbase + pt*8];
    floatx4 ws   = *(const floatx4*)&s_tab[rbase + pt*8 + 4];
    floatx4 v0 = *(const floatx4*)(vb + offs.x);
    floatx4 v1 = *(const floatx4*)(vb + offs.y);
    floatx4 v2 = *(const floatx4*)(vb + offs.z);
    floatx4 v3 = *(const floatx4*)(vb + offs.w);
    acc += ws.x * v0;
    acc += ws.y * v1;
    acc += ws.z * v2;
    acc += ws.w * v3;
  }
  int m = mbase + ql;
  *(floatx4*)&tmp[(size_t)m * DIM + h*HD + cq*4] = acc;   // [b,q,ch] coalesced
}

// ---------------- transpose tmp[b,q,ch] -> out[b,ch,q] ----------------
__global__ __launch_bounds__(256) void transpose_kernel(
    const float* __restrict__ tmp, float* __restrict__ out) {
  __shared__ float tile[32][33];
  const int b  = blockIdx.z;
  const int q0 = blockIdx.x * 32;
  const int c0 = blockIdx.y * 32;
  const int tx = threadIdx.x & 31;
  const int ty = threadIdx.x >> 5;   // 0..7
  #pragma unroll
  for (int i = 0; i < 4; i++) {
    int qq = q0 + ty + i*8;
    tile[ty + i*8][tx] = (qq < NQ) ? tmp[((long)b*NQ + qq)*DIM + c0 + tx] : 0.f;
  }
  __syncthreads();
  if (q0 + tx < NQ) {
    #pragma unroll
    for (int i = 0; i < 4; i++) {
      out[((long)b*DIM + c0 + ty + i*8)*NQ + q0 + tx] = tile[tx][ty + i*8];
    }
  }
}

extern "C" void kernel_launch(void* const* d_in, const int* in_sizes, int n_in,
                              void* d_out, int out_size, void* d_ws, size_t ws_size,
                              hipStream_t stream) {
  const float* query  = (const float*)d_in[0];
  const float* value  = (const float*)d_in[1];
  const float* refp   = (const float*)d_in[2];
  // d_in[3] = spatial_shapes (constants hardcoded)
  const float* W_off  = (const float*)d_in[4];
  const float* b_off  = (const float*)d_in[5];
  const float* W_attn = (const float*)d_in[6];
  const float* b_attn = (const float*)d_in[7];
  float* out = (float*)d_out;

  char* ws = (char*)d_ws;
  float* raw = (float*)ws;                         // 30,720,000 B
  float* tmp = (float*)(ws + 30720000);            // 20,480,000 B

  hipLaunchKernelGGL(gemm_kernel, dim3(3, 313), dim3(256), 0, stream,
                     query, W_off, W_attn, b_off, b_attn, raw);
  hipLaunchKernelGGL(sample_kernel, dim3(NQ / 4, BSZ), dim3(256), 0, stream,
                     raw, value, refp, tmp);
  hipLaunchKernelGGL(transpose_kernel, dim3(313, 8, 2), dim3(256), 0, stream,
                     tmp, out);
}

// Round 6
// 177.016 us; speedup vs baseline: 1.0589x; 1.0083x over previous
//
#include <hip/hip_runtime.h>

#define NQ   10000
#define BSZ  2
#define DIM  256
#define NH   8
#define HD   32
#define NLV  4
#define NPT  4
#define NV   13294           // 10000 + 2500 + 625 + 169
#define MT   (BSZ*NQ)        // 20000 rows
#define NOUT 384             // 256 offsets + 128 attn logits
#define NVAL (BSZ*NV*NH*HD)  // 6,806,528 f32 elements in value

typedef float  floatx4 __attribute__((ext_vector_type(4)));
typedef int    intx4   __attribute__((ext_vector_type(4)));
typedef __bf16 bf16x8  __attribute__((ext_vector_type(8)));

__device__ __forceinline__ unsigned short f32_to_bf16(float f) {
  unsigned int u = __float_as_uint(f);
  u += 0x7FFFu + ((u >> 16) & 1u);   // RNE
  return (unsigned short)(u >> 16);
}

// ---------------- prep: value f32 -> bf16 (halves gather sector traffic) ----------------
__global__ __launch_bounds__(256) void prep_kernel(
    const float* __restrict__ value, unsigned short* __restrict__ vb16) {
  int i = blockIdx.x * 256 + threadIdx.x;   // one float4 per thread
  if (i * 4 < NVAL) {
    floatx4 v = *(const floatx4*)&value[i * 4];
    unsigned short t[4] = { f32_to_bf16(v.x), f32_to_bf16(v.y),
                            f32_to_bf16(v.z), f32_to_bf16(v.w) };
    *(uint2*)&vb16[i * 4] = *(const uint2*)t;
  }
}

// ---------------- fused cast+GEMM: raw = Q @ [W_off;W_attn]^T + bias ----------------
// block tile 64(m) x 128(n), BK=32, 4 waves; f32->bf16 in registers during staging.
__global__ __launch_bounds__(256) void gemm_kernel(
    const float* __restrict__ query, const float* __restrict__ W_off,
    const float* __restrict__ W_attn,
    const float* __restrict__ b_off, const float* __restrict__ b_attn,
    float* __restrict__ raw) {
  __shared__ unsigned short As[64][40];    // +8 pad
  __shared__ unsigned short Bs[128][40];
  const int n0 = blockIdx.x * 128;
  const int m0 = blockIdx.y * 64;
  const int tid  = threadIdx.x;
  const int wave = tid >> 6;
  const int lane = tid & 63;
  const int quad = lane >> 4;
  const int l16  = lane & 15;
  floatx4 acc[8] = {};
  const int ar = tid >> 2;        // 0..63
  const int ac = (tid & 3) * 8;   // 0,8,16,24
  const int br = tid >> 1;        // 0..127
  const int bc = (tid & 1) * 16;  // 0,16
  const float* __restrict__ Wsrc =
      (n0 < 256) ? (W_off + (size_t)n0 * DIM) : (W_attn + (size_t)(n0 - 256) * DIM);

  for (int k0 = 0; k0 < DIM; k0 += 32) {
    {
      int gm = m0 + ar;
      floatx4 a0 = {}, a1 = {};
      if (gm < MT) {
        const float* src = query + (size_t)gm * DIM + k0 + ac;
        a0 = *(const floatx4*)src;
        a1 = *(const floatx4*)(src + 4);
      }
      unsigned short t[8];
      t[0]=f32_to_bf16(a0.x); t[1]=f32_to_bf16(a0.y); t[2]=f32_to_bf16(a0.z); t[3]=f32_to_bf16(a0.w);
      t[4]=f32_to_bf16(a1.x); t[5]=f32_to_bf16(a1.y); t[6]=f32_to_bf16(a1.z); t[7]=f32_to_bf16(a1.w);
      *(uint4*)&As[ar][ac] = *(const uint4*)t;
    }
    {
      const float* src = Wsrc + (size_t)br * DIM + k0 + bc;
      floatx4 b0 = *(const floatx4*)src;
      floatx4 b1 = *(const floatx4*)(src + 4);
      floatx4 b2 = *(const floatx4*)(src + 8);
      floatx4 b3 = *(const floatx4*)(src + 12);
      unsigned short t[16];
      t[0]=f32_to_bf16(b0.x);  t[1]=f32_to_bf16(b0.y);  t[2]=f32_to_bf16(b0.z);  t[3]=f32_to_bf16(b0.w);
      t[4]=f32_to_bf16(b1.x);  t[5]=f32_to_bf16(b1.y);  t[6]=f32_to_bf16(b1.z);  t[7]=f32_to_bf16(b1.w);
      t[8]=f32_to_bf16(b2.x);  t[9]=f32_to_bf16(b2.y);  t[10]=f32_to_bf16(b2.z); t[11]=f32_to_bf16(b2.w);
      t[12]=f32_to_bf16(b3.x); t[13]=f32_to_bf16(b3.y); t[14]=f32_to_bf16(b3.z); t[15]=f32_to_bf16(b3.w);
      *(uint4*)&Bs[br][bc]     = *(const uint4*)t;
      *(uint4*)&Bs[br][bc + 8] = *(const uint4*)(t + 8);
    }
    __syncthreads();
    bf16x8 a = *(const bf16x8*)&As[wave*16 + l16][quad*8];
    #pragma unroll
    for (int nt = 0; nt < 8; nt++) {
      bf16x8 b = *(const bf16x8*)&Bs[nt*16 + l16][quad*8];
      acc[nt] = __builtin_amdgcn_mfma_f32_16x16x32_bf16(a, b, acc[nt], 0, 0, 0);
    }
    __syncthreads();
  }
  #pragma unroll
  for (int nt = 0; nt < 8; nt++) {
    int gn = n0 + nt*16 + l16;
    float bias = (gn < 256) ? b_off[gn] : b_attn[gn - 256];
    #pragma unroll
    for (int r = 0; r < 4; r++) {
      int gm = m0 + wave*16 + quad*4 + r;
      if (gm < MT) raw[(size_t)gm*NOUT + gn] = acc[nt][r] + bias;
    }
  }
}

// ---------------- softmax + bilinear sampling (bf16 value gathers) ----------------
// Block = 256 threads, FOUR queries. LDS 19,072 B.
//  1) 512 slots (ql,h,l,p): logits -> s_aw (17-stride); px,py in REGISTERS
//  2) softmax per (ql,h) (32 threads), in place
//  3) tap table: bf16 byte-offset (idx*512 + h*64; OOB -> 0) + aw-folded weight
//  4) accumulate: wave=ql, lane=(h,cq): 16 pts x (2 ds_read_b128 +
//     4 global_load_dwordx2 bf16 + unpack + 16 fma); float4 store to tmp[b,q,ch]
__global__ __launch_bounds__(256) void sample_kernel(
    const float* __restrict__ raw, const unsigned short* __restrict__ vb16,
    const float* __restrict__ refp, float* __restrict__ tmp) {
  const int b  = blockIdx.y;
  const int q0 = blockIdx.x * 4;
  const int mbase = b * NQ + q0;
  const int tid = threadIdx.x;

  __shared__ int   s_tab[4 * 8 * 132];   // 16,896 B
  __shared__ float s_aw[544];            //  2,176 B

  const int WLI[4] = {100, 50, 25, 13};
  const int STI[4] = {0, 10000, 12500, 13125};

  float rpx[2], rpy[2];

  // ---- phase 1 ----
  #pragma unroll
  for (int it = 0; it < 2; ++it) {
    int slot = it * 256 + tid;
    int ql = slot >> 7, r = slot & 127, h = r >> 4, lp = r & 15, l = lp >> 2, p = lp & 3;
    int m = mbase + ql;
    const float* rp = raw + (size_t)m * NOUT;
    float offx = rp[h*32 + l*8 + p*2 + 0];
    float offy = rp[h*32 + l*8 + p*2 + 1];
    s_aw[(ql*8 + h)*17 + lp] = rp[256 + h*16 + lp];
    float Wl = (float)WLI[l];
    float rx = refp[(m*NLV + l)*2 + 0];
    float ry = refp[(m*NLV + l)*2 + 1];
    rpx[it] = rx * Wl + offx - 0.5f;
    rpy[it] = ry * Wl + offy - 0.5f;
  }
  __syncthreads();

  // ---- phase 2: softmax ----
  if (tid < 32) {
    int base = tid * 17;
    float mx = -1e30f;
    #pragma unroll
    for (int i = 0; i < 16; i++) mx = fmaxf(mx, s_aw[base + i]);
    float s = 0.f;
    float e[16];
    #pragma unroll
    for (int i = 0; i < 16; i++) { e[i] = expf(s_aw[base + i] - mx); s += e[i]; }
    float inv = 1.f / s;
    #pragma unroll
    for (int i = 0; i < 16; i++) s_aw[base + i] = e[i] * inv;
  }
  __syncthreads();

  // ---- phase 3: tap table (bf16 byte offsets + folded weights) ----
  #pragma unroll
  for (int it = 0; it < 2; ++it) {
    int slot = it * 256 + tid;
    int ql = slot >> 7, r = slot & 127, h = r >> 4, lp = r & 15, l = lp >> 2;
    float aw = s_aw[(ql*8 + h)*17 + lp];
    float px = rpx[it], py = rpy[it];
    float x0f = floorf(px), y0f = floorf(py);
    int x0 = (int)x0f, y0 = (int)y0f;
    float wx1 = px - x0f, wx0 = 1.f - wx1;
    float wy1 = py - y0f, wy0 = 1.f - wy1;
    int Wl = WLI[l], STl = STI[l];
    int row = (ql*8 + h) * 132 + lp * 8;
    #pragma unroll
    for (int t = 0; t < 4; ++t) {
      int xi = x0 + (t & 1), yi = y0 + (t >> 1);
      bool inb = (xi >= 0) & (xi < Wl) & (yi >= 0) & (yi < Wl);
      int off = inb ? ((STl + yi*Wl + xi) * 512 + h * 64) : 0;  // bf16 bytes
      float w = inb ? (aw * ((t & 1) ? wx1 : wx0) * ((t >> 1) ? wy1 : wy0)) : 0.f;
      s_tab[row + t]     = off;
      s_tab[row + 4 + t] = __float_as_int(w);
    }
  }
  __syncthreads();

  // ---- phase 4: accumulate; wave = query, lane = (h, cq) ----
  const int ql = tid >> 6, lane = tid & 63, h = lane >> 3, cq = lane & 7;
  const char* vb = (const char*)vb16 + (size_t)b * (NV*NH*HD*2) + cq * 8;
  floatx4 acc = {0.f, 0.f, 0.f, 0.f};
  const int rbase = (ql*8 + h) * 132;
  #pragma unroll 4
  for (int pt = 0; pt < 16; ++pt) {
    intx4   offs = *(const intx4*)  &s_tab[rbase + pt*8];
    floatx4 ws   = *(const floatx4*)&s_tab[rbase + pt*8 + 4];
    uint2 u0 = *(const uint2*)(vb + offs.x);
    uint2 u1 = *(const uint2*)(vb + offs.y);
    uint2 u2 = *(const uint2*)(vb + offs.z);
    uint2 u3 = *(const uint2*)(vb + offs.w);
    #pragma unroll
    for (int t = 0; t < 4; ++t) {
      uint2 u = (t == 0) ? u0 : (t == 1) ? u1 : (t == 2) ? u2 : u3;
      float w = (t == 0) ? ws.x : (t == 1) ? ws.y : (t == 2) ? ws.z : ws.w;
      acc.x += w * __uint_as_float(u.x << 16);
      acc.y += w * __uint_as_float(u.x & 0xFFFF0000u);
      acc.z += w * __uint_as_float(u.y << 16);
      acc.w += w * __uint_as_float(u.y & 0xFFFF0000u);
    }
  }
  int m = mbase + ql;
  *(floatx4*)&tmp[(size_t)m * DIM + h*HD + cq*4] = acc;   // [b,q,ch] coalesced
}

// ---------------- transpose tmp[b,q,ch] -> out[b,ch,q] ----------------
__global__ __launch_bounds__(256) void transpose_kernel(
    const float* __restrict__ tmp, float* __restrict__ out) {
  __shared__ float tile[32][33];
  const int b  = blockIdx.z;
  const int q0 = blockIdx.x * 32;
  const int c0 = blockIdx.y * 32;
  const int tx = threadIdx.x & 31;
  const int ty = threadIdx.x >> 5;   // 0..7
  #pragma unroll
  for (int i = 0; i < 4; i++) {
    int qq = q0 + ty + i*8;
    tile[ty + i*8][tx] = (qq < NQ) ? tmp[((long)b*NQ + qq)*DIM + c0 + tx] : 0.f;
  }
  __syncthreads();
  if (q0 + tx < NQ) {
    #pragma unroll
    for (int i = 0; i < 4; i++) {
      out[((long)b*DIM + c0 + ty + i*8)*NQ + q0 + tx] = tile[tx][ty + i*8];
    }
  }
}

extern "C" void kernel_launch(void* const* d_in, const int* in_sizes, int n_in,
                              void* d_out, int out_size, void* d_ws, size_t ws_size,
                              hipStream_t stream) {
  const float* query  = (const float*)d_in[0];
  const float* value  = (const float*)d_in[1];
  const float* refp   = (const float*)d_in[2];
  // d_in[3] = spatial_shapes (constants hardcoded)
  const float* W_off  = (const float*)d_in[4];
  const float* b_off  = (const float*)d_in[5];
  const float* W_attn = (const float*)d_in[6];
  const float* b_attn = (const float*)d_in[7];
  float* out = (float*)d_out;

  char* ws = (char*)d_ws;
  float*          raw  = (float*)ws;                      // 30,720,000 B
  float*          tmp  = (float*)(ws + 30720000);         // 20,480,000 B
  unsigned short* vb16 = (unsigned short*)(ws + 51200000);// 13,613,056 B

  hipLaunchKernelGGL(prep_kernel, dim3((NVAL/4 + 255) / 256), dim3(256), 0, stream,
                     value, vb16);
  hipLaunchKernelGGL(gemm_kernel, dim3(3, 313), dim3(256), 0, stream,
                     query, W_off, W_attn, b_off, b_attn, raw);
  hipLaunchKernelGGL(sample_kernel, dim3(NQ / 4, BSZ), dim3(256), 0, stream,
                     raw, vb16, refp, tmp);
  hipLaunchKernelGGL(transpose_kernel, dim3(313, 8, 2), dim3(256), 0, stream,
                     tmp, out);
}

// Round 7
// 168.970 us; speedup vs baseline: 1.1093x; 1.0476x over previous
//
#include <hip/hip_runtime.h>

#define NQ   10000
#define BSZ  2
#define DIM  256
#define NH   8
#define HD   32
#define NLV  4
#define NPT  4
#define NV   13294           // 10000 + 2500 + 625 + 169
#define MT   (BSZ*NQ)        // 20000 rows
#define NOUT 384             // 256 offsets + 128 attn logits
#define NVAL (BSZ*NV*NH*HD)  // 6,806,528 f32 elements in value
#define GEMM_BLOCKS 939      // 3 x 313
#define PREP_BLOCKS 6647     // NVAL/4/256

typedef float  floatx4 __attribute__((ext_vector_type(4)));
typedef int    intx4   __attribute__((ext_vector_type(4)));
typedef __bf16 bf16x8  __attribute__((ext_vector_type(8)));

__device__ __forceinline__ unsigned short f32_to_bf16(float f) {
  unsigned int u = __float_as_uint(f);
  u += 0x7FFFu + ((u >> 16) & 1u);   // RNE
  return (unsigned short)(u >> 16);
}

// ---------------- merged prep + GEMM (independent work, overlapped on CUs) ----------
// bid < GEMM_BLOCKS: 64x128 MFMA tile of raw = Q @ [W_off;W_attn]^T + bias
// else:              value f32 -> bf16 cast (one float4 per thread)
__global__ __launch_bounds__(256) void gp_kernel(
    const float* __restrict__ query, const float* __restrict__ W_off,
    const float* __restrict__ W_attn,
    const float* __restrict__ b_off, const float* __restrict__ b_attn,
    const float* __restrict__ value,
    float* __restrict__ raw, unsigned short* __restrict__ vb16) {
  const int bid = blockIdx.x;
  const int tid = threadIdx.x;
  if (bid >= GEMM_BLOCKS) {          // ---- prep part ----
    int i = (bid - GEMM_BLOCKS) * 256 + tid;
    if (i * 4 < NVAL) {
      floatx4 v = *(const floatx4*)&value[i * 4];
      unsigned short t[4] = { f32_to_bf16(v.x), f32_to_bf16(v.y),
                              f32_to_bf16(v.z), f32_to_bf16(v.w) };
      *(uint2*)&vb16[i * 4] = *(const uint2*)t;
    }
    return;
  }
  // ---- gemm part ----
  __shared__ unsigned short As[64][40];    // +8 pad
  __shared__ unsigned short Bs[128][40];
  const int n0 = (bid % 3) * 128;
  const int m0 = (bid / 3) * 64;
  const int wave = tid >> 6;
  const int lane = tid & 63;
  const int quad = lane >> 4;
  const int l16  = lane & 15;
  floatx4 acc[8] = {};
  const int ar = tid >> 2;        // 0..63
  const int ac = (tid & 3) * 8;   // 0,8,16,24
  const int br = tid >> 1;        // 0..127
  const int bc = (tid & 1) * 16;  // 0,16
  const float* __restrict__ Wsrc =
      (n0 < 256) ? (W_off + (size_t)n0 * DIM) : (W_attn + (size_t)(n0 - 256) * DIM);

  for (int k0 = 0; k0 < DIM; k0 += 32) {
    {
      int gm = m0 + ar;
      floatx4 a0 = {}, a1 = {};
      if (gm < MT) {
        const float* src = query + (size_t)gm * DIM + k0 + ac;
        a0 = *(const floatx4*)src;
        a1 = *(const floatx4*)(src + 4);
      }
      unsigned short t[8];
      t[0]=f32_to_bf16(a0.x); t[1]=f32_to_bf16(a0.y); t[2]=f32_to_bf16(a0.z); t[3]=f32_to_bf16(a0.w);
      t[4]=f32_to_bf16(a1.x); t[5]=f32_to_bf16(a1.y); t[6]=f32_to_bf16(a1.z); t[7]=f32_to_bf16(a1.w);
      *(uint4*)&As[ar][ac] = *(const uint4*)t;
    }
    {
      const float* src = Wsrc + (size_t)br * DIM + k0 + bc;
      floatx4 b0 = *(const floatx4*)src;
      floatx4 b1 = *(const floatx4*)(src + 4);
      floatx4 b2 = *(const floatx4*)(src + 8);
      floatx4 b3 = *(const floatx4*)(src + 12);
      unsigned short t[16];
      t[0]=f32_to_bf16(b0.x);  t[1]=f32_to_bf16(b0.y);  t[2]=f32_to_bf16(b0.z);  t[3]=f32_to_bf16(b0.w);
      t[4]=f32_to_bf16(b1.x);  t[5]=f32_to_bf16(b1.y);  t[6]=f32_to_bf16(b1.z);  t[7]=f32_to_bf16(b1.w);
      t[8]=f32_to_bf16(b2.x);  t[9]=f32_to_bf16(b2.y);  t[10]=f32_to_bf16(b2.z); t[11]=f32_to_bf16(b2.w);
      t[12]=f32_to_bf16(b3.x); t[13]=f32_to_bf16(b3.y); t[14]=f32_to_bf16(b3.z); t[15]=f32_to_bf16(b3.w);
      *(uint4*)&Bs[br][bc]     = *(const uint4*)t;
      *(uint4*)&Bs[br][bc + 8] = *(const uint4*)(t + 8);
    }
    __syncthreads();
    bf16x8 a = *(const bf16x8*)&As[wave*16 + l16][quad*8];
    #pragma unroll
    for (int nt = 0; nt < 8; nt++) {
      bf16x8 b = *(const bf16x8*)&Bs[nt*16 + l16][quad*8];
      acc[nt] = __builtin_amdgcn_mfma_f32_16x16x32_bf16(a, b, acc[nt], 0, 0, 0);
    }
    __syncthreads();
  }
  #pragma unroll
  for (int nt = 0; nt < 8; nt++) {
    int gn = n0 + nt*16 + l16;
    float bias = (gn < 256) ? b_off[gn] : b_attn[gn - 256];
    #pragma unroll
    for (int r = 0; r < 4; r++) {
      int gm = m0 + wave*16 + quad*4 + r;
      if (gm < MT) raw[(size_t)gm*NOUT + gn] = acc[nt][r] + bias;
    }
  }
}

// ---------------- softmax + bilinear sampling ----------------
// Block = 256 threads = 4 waves, EIGHT queries (2 per wave). LDS 30,464 B -> 5 blk/CU.
//  1) 1024 slots (ql,h,l,p): logits -> s_aw (17-stride); px,py in REGISTERS
//  2) softmax per (ql,h): 64 rows, one full wave
//  3) s_off[(ql*8+h)*68 + lp*4] = 4 tap byte-offsets (idx*512+h*64; OOB->0)
//     s_w [(ql*8+h)*34 + lp*2] = 4 aw-folded weights as packed bf16 pairs
//  4) wave = 2 queries; lane=(qh,h,cq): 16 pts x (ds_read_b128 + ds_read_b64 +
//     4 global_load_dwordx4 (16B/lane, 8ch) + unpack+fma); 2x float4 store to tmp
__global__ __launch_bounds__(256) void sample_kernel(
    const float* __restrict__ raw, const unsigned short* __restrict__ vb16,
    const float* __restrict__ refp, float* __restrict__ tmp) {
  const int b  = blockIdx.y;
  const int q0 = blockIdx.x * 8;
  const int mbase = b * NQ + q0;
  const int tid = threadIdx.x;

  __shared__ int          s_off[64 * 68];   // 17,408 B
  __shared__ unsigned int s_w  [64 * 34];   //  8,704 B
  __shared__ float        s_aw [64 * 17];   //  4,352 B

  const int WLI[4] = {100, 50, 25, 13};
  const int STI[4] = {0, 10000, 12500, 13125};

  float rpx[4], rpy[4];

  // ---- phase 1: coords (registers) + logits (LDS) ----
  #pragma unroll
  for (int it = 0; it < 4; ++it) {
    int slot = it * 256 + tid;
    int ql = slot >> 7, r = slot & 127, h = r >> 4, lp = r & 15, l = lp >> 2, p = lp & 3;
    int m = mbase + ql;
    const float* rp = raw + (size_t)m * NOUT;
    float offx = rp[h*32 + l*8 + p*2 + 0];
    float offy = rp[h*32 + l*8 + p*2 + 1];
    s_aw[(ql*8 + h)*17 + lp] = rp[256 + h*16 + lp];
    float Wl = (float)WLI[l];
    float rx = refp[(m*NLV + l)*2 + 0];
    float ry = refp[(m*NLV + l)*2 + 1];
    // (ref + off/W)*2-1 -> pixel (align_corners=False): ref*W + off - 0.5
    rpx[it] = rx * Wl + offx - 0.5f;
    rpy[it] = ry * Wl + offy - 0.5f;
  }
  __syncthreads();

  // ---- phase 2: softmax over 16 logits per (ql,h), in place; one full wave ----
  if (tid < 64) {
    int base = tid * 17;
    float mx = -1e30f;
    #pragma unroll
    for (int i = 0; i < 16; i++) mx = fmaxf(mx, s_aw[base + i]);
    float s = 0.f;
    float e[16];
    #pragma unroll
    for (int i = 0; i < 16; i++) { e[i] = expf(s_aw[base + i] - mx); s += e[i]; }
    float inv = 1.f / s;
    #pragma unroll
    for (int i = 0; i < 16; i++) s_aw[base + i] = e[i] * inv;
  }
  __syncthreads();

  // ---- phase 3: tap offsets + packed bf16 weights ----
  #pragma unroll
  for (int it = 0; it < 4; ++it) {
    int slot = it * 256 + tid;
    int ql = slot >> 7, r = slot & 127, h = r >> 4, lp = r & 15, l = lp >> 2;
    int rowqh = ql*8 + h;
    float aw = s_aw[rowqh*17 + lp];
    float px = rpx[it], py = rpy[it];
    float x0f = floorf(px), y0f = floorf(py);
    int x0 = (int)x0f, y0 = (int)y0f;
    float wx1 = px - x0f, wx0 = 1.f - wx1;
    float wy1 = py - y0f, wy0 = 1.f - wy1;
    int Wl = WLI[l], STl = STI[l];
    int offs[4]; unsigned short wb[4];
    #pragma unroll
    for (int t = 0; t < 4; ++t) {
      int xi = x0 + (t & 1), yi = y0 + (t >> 1);
      bool inb = (xi >= 0) & (xi < Wl) & (yi >= 0) & (yi < Wl);
      offs[t] = inb ? ((STl + yi*Wl + xi) * 512 + h * 64) : 0;  // bf16 bytes
      float w = inb ? (aw * ((t & 1) ? wx1 : wx0) * ((t >> 1) ? wy1 : wy0)) : 0.f;
      wb[t] = f32_to_bf16(w);
    }
    *(intx4*)&s_off[rowqh*68 + lp*4] = *(const intx4*)offs;
    uint2 wp = { (unsigned)wb[0] | ((unsigned)wb[1] << 16),
                 (unsigned)wb[2] | ((unsigned)wb[3] << 16) };
    *(uint2*)&s_w[rowqh*34 + lp*2] = wp;
  }
  __syncthreads();

  // ---- phase 4: accumulate; wave = 2 queries, lane = (qh, h, cq) ----
  const int wv = tid >> 6, lane = tid & 63;
  const int qh = lane >> 5, ql = wv*2 + qh;
  const int h = (lane >> 2) & 7, cq = lane & 3;
  const char* vb = (const char*)vb16 + (size_t)b * (NV*NH*HD*2) + cq * 16;
  floatx4 acc0 = {0.f,0.f,0.f,0.f}, acc1 = {0.f,0.f,0.f,0.f};
  const int orow = (ql*8 + h) * 68, wrow = (ql*8 + h) * 34;
  #pragma unroll 4
  for (int pt = 0; pt < 16; ++pt) {
    intx4 offs = *(const intx4*)&s_off[orow + pt*4];
    uint2 wp   = *(const uint2*)&s_w[wrow + pt*2];
    float w0 = __uint_as_float(wp.x << 16);
    float w1 = __uint_as_float(wp.x & 0xFFFF0000u);
    float w2 = __uint_as_float(wp.y << 16);
    float w3 = __uint_as_float(wp.y & 0xFFFF0000u);
    uint4 u0 = *(const uint4*)(vb + offs.x);
    uint4 u1 = *(const uint4*)(vb + offs.y);
    uint4 u2 = *(const uint4*)(vb + offs.z);
    uint4 u3 = *(const uint4*)(vb + offs.w);
    #pragma unroll
    for (int t = 0; t < 4; ++t) {
      uint4 u = (t==0) ? u0 : (t==1) ? u1 : (t==2) ? u2 : u3;
      float w = (t==0) ? w0 : (t==1) ? w1 : (t==2) ? w2 : w3;
      acc0.x += w * __uint_as_float(u.x << 16);
      acc0.y += w * __uint_as_float(u.x & 0xFFFF0000u);
      acc0.z += w * __uint_as_float(u.y << 16);
      acc0.w += w * __uint_as_float(u.y & 0xFFFF0000u);
      acc1.x += w * __uint_as_float(u.z << 16);
      acc1.y += w * __uint_as_float(u.z & 0xFFFF0000u);
      acc1.z += w * __uint_as_float(u.w << 16);
      acc1.w += w * __uint_as_float(u.w & 0xFFFF0000u);
    }
  }
  int m = mbase + ql;
  float* dst = &tmp[(size_t)m * DIM + h*HD + cq*8];
  *(floatx4*)dst       = acc0;
  *(floatx4*)(dst + 4) = acc1;
}

// ---------------- transpose tmp[b,q,ch] -> out[b,ch,q] ----------------
__global__ __launch_bounds__(256) void transpose_kernel(
    const float* __restrict__ tmp, float* __restrict__ out) {
  __shared__ float tile[32][33];
  const int b  = blockIdx.z;
  const int q0 = blockIdx.x * 32;
  const int c0 = blockIdx.y * 32;
  const int tx = threadIdx.x & 31;
  const int ty = threadIdx.x >> 5;   // 0..7
  #pragma unroll
  for (int i = 0; i < 4; i++) {
    int qq = q0 + ty + i*8;
    tile[ty + i*8][tx] = (qq < NQ) ? tmp[((long)b*NQ + qq)*DIM + c0 + tx] : 0.f;
  }
  __syncthreads();
  if (q0 + tx < NQ) {
    #pragma unroll
    for (int i = 0; i < 4; i++) {
      out[((long)b*DIM + c0 + ty + i*8)*NQ + q0 + tx] = tile[tx][ty + i*8];
    }
  }
}

extern "C" void kernel_launch(void* const* d_in, const int* in_sizes, int n_in,
                              void* d_out, int out_size, void* d_ws, size_t ws_size,
                              hipStream_t stream) {
  const float* query  = (const float*)d_in[0];
  const float* value  = (const float*)d_in[1];
  const float* refp   = (const float*)d_in[2];
  // d_in[3] = spatial_shapes (constants hardcoded)
  const float* W_off  = (const float*)d_in[4];
  const float* b_off  = (const float*)d_in[5];
  const float* W_attn = (const float*)d_in[6];
  const float* b_attn = (const float*)d_in[7];
  float* out = (float*)d_out;

  char* ws = (char*)d_ws;
  float*          raw  = (float*)ws;                      // 30,720,000 B
  float*          tmp  = (float*)(ws + 30720000);         // 20,480,000 B
  unsigned short* vb16 = (unsigned short*)(ws + 51200000);// 13,613,056 B

  hipLaunchKernelGGL(gp_kernel, dim3(GEMM_BLOCKS + PREP_BLOCKS), dim3(256), 0, stream,
                     query, W_off, W_attn, b_off, b_attn, value, raw, vb16);
  hipLaunchKernelGGL(sample_kernel, dim3(NQ / 8, BSZ), dim3(256), 0, stream,
                     raw, vb16, refp, tmp);
  hipLaunchKernelGGL(transpose_kernel, dim3(313, 8, 2), dim3(256), 0, stream,
                     tmp, out);
}